// Round 7
// baseline (103.891 us; speedup 1.0000x reference)
//
#include <hip/hip_runtime.h>
#include <hip/hip_bf16.h>

#define NUP 8
#define NDOWN 8
#define NMO 32
#define NCONF 64
#define NBATCH 16384
#define BPB 4              // batches per 256-thread block; one wave per batch
#define ROWSTRIDE 33       // padded row stride (dwords): bank = (c + r) % 32 -> no column aliasing
#define PANEL (16 * ROWSTRIDE)  // 528 dwords per batch panel

// 8x8 determinant via fully-unrolled Gaussian elimination with partial
// pivoting. All indices compile-time after unrolling -> stays in VGPRs
// (runtime-indexed register arrays would go to scratch, rule #20).
// Sign-free pivoting: {row_k <- row_i; row_i <- -row_k} preserves det and
// the negation folds into the cndmask source modifier; |.| compares are
// sign-blind so later pivot searches are unaffected.
__device__ __forceinline__ float det8(const float* __restrict__ base,
                                      int4 ca, int4 cb) {
    float m[8][8];
    const int cols[8] = {ca.x, ca.y, ca.z, ca.w, cb.x, cb.y, cb.z, cb.w};
#pragma unroll
    for (int j = 0; j < 8; ++j) {
        const float* cp = base + cols[j];
        // One v_lshl_add per column, then 8 ds_read with imm offsets
        // i*132B (pairs mergeable into ds_read2_b32: offsets 0,33 dwords).
#pragma unroll
        for (int i = 0; i < 8; ++i) {
            m[i][j] = cp[i * ROWSTRIDE];
        }
    }

    float det = 1.0f;
#pragma unroll
    for (int k = 0; k < 8; ++k) {
        // Static compare-and-pseudo-swap chain: row k ends with the max-|.|
        // pivot among rows k..7 (same row choice as LAPACK, first-max ties).
#pragma unroll
        for (int i = k + 1; i < 8; ++i) {
            bool sw = fabsf(m[i][k]) > fabsf(m[k][k]);  // abs folds into v_cmp
#pragma unroll
            for (int j = k; j < 8; ++j) {
                float a = m[k][j], b = m[i][j];
                m[k][j] = sw ? b : a;
                m[i][j] = sw ? -a : b;   // neg folds into cndmask src modifier
            }
        }
        det *= m[k][k];
        if (k < 7) {
            // v_rcp_f32 (2^-22 rel err) vs ~10-instr IEEE divide; det error
            // stays ~1e-6 relative, same order as fp32 LU noise.
            float r = __builtin_amdgcn_rcpf(m[k][k]);
#pragma unroll
            for (int i = k + 1; i < 8; ++i) {
                float f = m[i][k] * r;
#pragma unroll
                for (int j = k + 1; j < 8; ++j) {
                    m[i][j] = fmaf(-f, m[k][j], m[i][j]);
                }
            }
        }
    }
    return det;
}

__global__ __launch_bounds__(256) void slater_kernel(
        const float* __restrict__ inp,     // [NBATCH][16][NMO] f32
        const int*   __restrict__ cup,     // [NCONF][NUP]
        const int*   __restrict__ cdown,   // [NCONF][NDOWN]
        float*       __restrict__ out)     // [NBATCH][NCONF]
{
    // 4 wave-private panels; NO __syncthreads anywhere: each wave stages and
    // reads only its own panel (DS pipe is in-order per wave; the compiler
    // inserts the lgkmcnt wait for the write->read dependency), so the four
    // waves free-run and stagger their LDS-gather vs VALU phases.
    __shared__ float lds[BPB * PANEL];   // 8448 B

    const int tid   = threadIdx.x;
    const int lane  = tid & 63;
    const int bl    = tid >> 6;                 // wave id == batch slot
    const int batch = blockIdx.x * BPB + bl;
    const int conf  = lane;                     // wave covers all 64 confs

    // Index loads first: their (L2-hot) global-load latency overlaps the
    // panel staging below.
    const int4 u0 = reinterpret_cast<const int4*>(cup   + conf * NUP)[0];
    const int4 u1 = reinterpret_cast<const int4*>(cup   + conf * NUP)[1];
    const int4 d0 = reinterpret_cast<const int4*>(cdown + conf * NDOWN)[0];
    const int4 d1 = reinterpret_cast<const int4*>(cdown + conf * NDOWN)[1];

    // Wave-private staging: this wave's 2 KB panel -> padded LDS.
    // Coalesced: 2 float4 per lane covers 16 rows x 32 mos.
    float* p = lds + bl * PANEL;
    {
        const float4* src = reinterpret_cast<const float4*>(inp + (size_t)batch * 16 * NMO);
        const float4 a = src[lane];
        const float4 b = src[lane + 64];
        const int e0 = lane >> 3;          // row 0..7
        const int m0 = (lane & 7) * 4;     // mo 0,4,..28
        p[e0 * ROWSTRIDE + m0 + 0] = a.x;
        p[e0 * ROWSTRIDE + m0 + 1] = a.y;
        p[e0 * ROWSTRIDE + m0 + 2] = a.z;
        p[e0 * ROWSTRIDE + m0 + 3] = a.w;
        const int e1 = e0 + 8;             // row 8..15
        p[e1 * ROWSTRIDE + m0 + 0] = b.x;
        p[e1 * ROWSTRIDE + m0 + 1] = b.y;
        p[e1 * ROWSTRIDE + m0 + 2] = b.z;
        p[e1 * ROWSTRIDE + m0 + 3] = b.w;
    }
    // No barrier: per-wave DS ordering guarantees our reads see our writes.

    const float det_up = det8(p,                  u0, u1);
    const float det_dn = det8(p + 8 * ROWSTRIDE,  d0, d1);

    // Coalesced: 64 consecutive floats per wave.
    out[(size_t)batch * NCONF + conf] = det_up * det_dn;
}

extern "C" void kernel_launch(void* const* d_in, const int* in_sizes, int n_in,
                              void* d_out, int out_size, void* d_ws, size_t ws_size,
                              hipStream_t stream) {
    const float* inp   = reinterpret_cast<const float*>(d_in[0]);
    const int*   cup   = reinterpret_cast<const int*>(d_in[1]);
    const int*   cdown = reinterpret_cast<const int*>(d_in[2]);
    float*       out   = reinterpret_cast<float*>(d_out);

    dim3 grid(NBATCH / BPB);   // 4096 blocks
    dim3 block(256);
    slater_kernel<<<grid, block, 0, stream>>>(inp, cup, cdown, out);
}

// Round 8
// 97.583 us; speedup vs baseline: 1.0646x; 1.0646x over previous
//
#include <hip/hip_runtime.h>
#include <hip/hip_bf16.h>

#define NUP 8
#define NDOWN 8
#define NMO 32
#define NCONF 64
#define NBATCH 16384
#define BPB 2              // batches per 256-thread block: 2 waves per batch
#define ROWSTRIDE 33       // padded row stride (dwords): bank = (c + r) % 32 -> no column aliasing
#define PANEL (16 * ROWSTRIDE)  // 528 dwords per batch panel copy

// 8x8 determinant via fully-unrolled Gaussian elimination with partial
// pivoting. All indices compile-time after unrolling -> stays in VGPRs
// (runtime-indexed register arrays would go to scratch, rule #20).
// Sign-free pivoting: {row_k <- row_i; row_i <- -row_k} preserves det and
// the negation folds into the cndmask source modifier; |.| compares are
// sign-blind so later pivot searches are unaffected.
__device__ __forceinline__ float det8(const float* __restrict__ base,
                                      int4 ca, int4 cb) {
    float m[8][8];
    const int cols[8] = {ca.x, ca.y, ca.z, ca.w, cb.x, cb.y, cb.z, cb.w};
#pragma unroll
    for (int j = 0; j < 8; ++j) {
        const float* cp = base + cols[j];
        // 8 reads at imm offsets i*132B; pairs merge into ds_read2_b32
        // (offsets 0,33,66,..,231 dwords, all < 256 -> mergeable).
#pragma unroll
        for (int i = 0; i < 8; ++i) {
            m[i][j] = cp[i * ROWSTRIDE];
        }
    }

    float det = 1.0f;
#pragma unroll
    for (int k = 0; k < 8; ++k) {
        // Static compare-and-pseudo-swap chain: row k ends with the max-|.|
        // pivot among rows k..7 (same row choice as LAPACK, first-max ties).
#pragma unroll
        for (int i = k + 1; i < 8; ++i) {
            bool sw = fabsf(m[i][k]) > fabsf(m[k][k]);  // abs folds into v_cmp
#pragma unroll
            for (int j = k; j < 8; ++j) {
                float a = m[k][j], b = m[i][j];
                m[k][j] = sw ? b : a;
                m[i][j] = sw ? -a : b;   // neg folds into cndmask src modifier
            }
        }
        det *= m[k][k];
        if (k < 7) {
            // v_rcp_f32 (2^-22 rel err) vs ~10-instr IEEE divide; det error
            // stays ~1e-6 relative, same order as fp32 LU noise.
            float r = __builtin_amdgcn_rcpf(m[k][k]);
#pragma unroll
            for (int i = k + 1; i < 8; ++i) {
                float f = m[i][k] * r;
#pragma unroll
                for (int j = k + 1; j < 8; ++j) {
                    m[i][j] = fmaf(-f, m[k][j], m[i][j]);
                }
            }
        }
    }
    return det;
}

__global__ __launch_bounds__(256) void slater_kernel(
        const float* __restrict__ inp,     // [NBATCH][16][NMO] f32
        const int*   __restrict__ cup,     // [NCONF][NUP]
        const int*   __restrict__ cdown,   // [NCONF][NDOWN]
        float*       __restrict__ out)     // [NBATCH][NCONF]
{
    // Up/dn split across lane halves: lanes 0-31 compute det_up for confs
    // c..c+31, lanes 32-63 compute det_dn for the same confs; one
    // __shfl_xor(det,32) pairs them. Per-thread chain halves, wave count
    // doubles (32768) -> better latency hiding at equal total work.
    // 4 wave-private panels, NO barriers (per-wave DS ordering covers the
    // staging write -> gather read dependency).
    __shared__ float lds[4 * PANEL];   // 8448 B

    const int tid   = threadIdx.x;
    const int lane  = tid & 63;
    const int w     = tid >> 6;            // wave 0..3
    const int bslot = w >> 1;              // batch slot in block
    const int wib   = w & 1;               // wave-in-batch: conf half
    const int batch = blockIdx.x * BPB + bslot;
    const int conf  = wib * 32 + (lane & 31);
    const bool up   = (lane < 32);

    // Per-lane index row: up-half reads cup, dn-half reads cdown.
    // Coalesced within each half (32 consecutive 32B rows); L2-hot.
    const int* cbase = up ? cup : cdown;
    const int4 c0 = reinterpret_cast<const int4*>(cbase + conf * 8)[0];
    const int4 c1 = reinterpret_cast<const int4*>(cbase + conf * 8)[1];

    // Wave-private staging of this batch's full 16x32 panel (each of the
    // batch's 2 waves keeps its own copy; 2nd global read hits L2).
    float* p = lds + w * PANEL;
    {
        const float4* src = reinterpret_cast<const float4*>(inp + (size_t)batch * 16 * NMO);
        const float4 a = src[lane];
        const float4 b = src[lane + 64];
        const int e0 = lane >> 3;          // row 0..7
        const int m0 = (lane & 7) * 4;     // mo 0,4,..28
        p[e0 * ROWSTRIDE + m0 + 0] = a.x;
        p[e0 * ROWSTRIDE + m0 + 1] = a.y;
        p[e0 * ROWSTRIDE + m0 + 2] = a.z;
        p[e0 * ROWSTRIDE + m0 + 3] = a.w;
        const int e1 = e0 + 8;             // row 8..15
        p[e1 * ROWSTRIDE + m0 + 0] = b.x;
        p[e1 * ROWSTRIDE + m0 + 1] = b.y;
        p[e1 * ROWSTRIDE + m0 + 2] = b.z;
        p[e1 * ROWSTRIDE + m0 + 3] = b.w;
    }
    // No barrier: per-wave DS ordering guarantees our reads see our writes.

    const float* base = p + (up ? 0 : 8 * ROWSTRIDE);
    const float det   = det8(base, c0, c1);

    // Pair lane L (det_up, conf) with lane L+32 (det_dn, same conf).
    const float other = __shfl_xor(det, 32);
    if (up) {
        out[(size_t)batch * NCONF + conf] = det * other;  // 32 consecutive f32
    }
}

extern "C" void kernel_launch(void* const* d_in, const int* in_sizes, int n_in,
                              void* d_out, int out_size, void* d_ws, size_t ws_size,
                              hipStream_t stream) {
    const float* inp   = reinterpret_cast<const float*>(d_in[0]);
    const int*   cup   = reinterpret_cast<const int*>(d_in[1]);
    const int*   cdown = reinterpret_cast<const int*>(d_in[2]);
    float*       out   = reinterpret_cast<float*>(d_out);

    dim3 grid(NBATCH / BPB);   // 8192 blocks
    dim3 block(256);
    slater_kernel<<<grid, block, 0, stream>>>(inp, cup, cdown, out);
}